// Round 4
// baseline (285.333 us; speedup 1.0000x reference)
//
#include <hip/hip_runtime.h>
#include <math.h>

#define Hdim 4096
#define NE 256
#define BM 64
#define BK 32
#define NKC (Hdim / BK)          // 128 K-chunks
#define PLANE_ELEMS (Hdim * NE)  // f16 elements per plane (1,048,576 = 2 MB)
#define PLANE_BYTES (PLANE_ELEMS * 2)

// Scales (exact powers of two; undone in epilogue):
//   W' = 64*w, X' = 16*x, m-planes additionally *2048.
//   logit = (acc0 + acc1*2^-11 + acc2*2^-22) * 2^-10
#define C0 9.765625e-4f            // 2^-10
#define C1 4.76837158203125e-7f    // 2^-21
#define C2 2.3283064365386963e-10f // 2^-32

typedef _Float16 f16x8 __attribute__((ext_vector_type(8)));
typedef float f32x4 __attribute__((ext_vector_type(4)));

__device__ __forceinline__ void gload_lds16(const void* g, void* l) {
  __builtin_amdgcn_global_load_lds((const __attribute__((address_space(1))) void*)g,
                                   (__attribute__((address_space(3))) void*)l, 16, 0, 0);
}

// ---------------------------------------------------------------------------
// W [256][4096] fp32 -> 2 f16 planes: h = f16(64w), m = f16((64w - h)*2048).
// Plane layout: [k8 0..511][n 0..255] chunks of 8 f16 (16 B): element (n,k)
// at plane + ((k/8)*256 + n)*8 + k%8 — the exact LDS image staged per chunk.
// ---------------------------------------------------------------------------
__global__ __launch_bounds__(256)
void convert_w(const float* __restrict__ W, _Float16* __restrict__ pl) {
  const int id = blockIdx.x * 256 + threadIdx.x;  // 0 .. 131071
  const int k8 = id & 511;
  const int n = id >> 9;
  const float* src = W + (long)n * Hdim + k8 * 8;
  const float4 x0 = *(const float4*)src;
  const float4 x1 = *(const float4*)(src + 4);
  const float xv[8] = {x0.x, x0.y, x0.z, x0.w, x1.x, x1.y, x1.z, x1.w};
  f16x8 vh, vm;
#pragma unroll
  for (int j = 0; j < 8; ++j) {
    const float v = xv[j] * 64.f;
    const _Float16 h = (_Float16)v;
    const float r = (v - (float)h) * 2048.f;
    vh[j] = h;
    vm[j] = (_Float16)r;
  }
  const long co = ((long)k8 * NE + n) * 8;
  *(f16x8*)(pl + co) = vh;
  *(f16x8*)(pl + PLANE_ELEMS + co) = vm;
}

// ---------------------------------------------------------------------------
// Fused: logits = X @ W^T via 4-product split-f16 MFMA, then top-k epilogue.
// 512 threads (8 waves as 2M x 4N), tile BM=64 tokens x all 256 experts.
// T3+T4 pipeline: 4-deep LDS ring of W chunk-buffers (4 x 32 KB), depth-3
// prefetch via global_load_lds, ONE raw s_barrier per chunk, counted
// s_waitcnt vmcnt(8) in steady state (full drain only in the 2-iter tail).
// X (A-operand) lives in registers: each lane loads its own 8 fp32 directly
// from global (issued one chunk early), converts to split-f16 in-reg.
// ---------------------------------------------------------------------------
__global__ __launch_bounds__(512)
void moe_gate_fused(const float* __restrict__ X, const _Float16* __restrict__ pl,
                    const float* __restrict__ bias, float* __restrict__ out, int T) {
  __shared__ __align__(16) unsigned char smem[131072];
  const int tid = threadIdx.x;
  const int lane = tid & 63, wave = tid >> 6;
  const int wm = wave >> 2, wn = wave & 3;
  const int r16 = lane & 15, c4 = lane >> 4;
  const long bm0 = (long)blockIdx.x * BM;

  f32x4 acc0[2][4], acc1[2][4], acc2[2][4];
#pragma unroll
  for (int i = 0; i < 2; ++i)
#pragma unroll
    for (int j = 0; j < 4; ++j) {
      acc0[i][j] = (f32x4)(0.f);
      acc1[i][j] = (f32x4)(0.f);
      acc2[i][j] = (f32x4)(0.f);
    }

  // per-lane A-fragment source rows: fm=0 -> row wm*32+r16, fm=1 -> +16
  const float* xsrcA = X + (bm0 + wm * 32 + r16) * (long)Hdim + c4 * 8;
  const float* xsrcB = xsrcA + 16 * (long)Hdim;

  float4 xc0, xc1, xc2, xc3, xn0, xn1, xn2, xn3;

#define STAGE_W(b, kc_)                                                         \
  {                                                                             \
    _Pragma("unroll") for (int p = 0; p < 2; ++p)                               \
        _Pragma("unroll") for (int i = 0; i < 2; ++i) {                         \
      const char* g = (const char*)pl + (size_t)p * PLANE_BYTES +               \
                      (size_t)(kc_) * 16384 + (size_t)(i * 512 + tid) * 16;     \
      void* l = (void*)&smem[(b) * 32768 + p * 16384 +                          \
                             (i * 512 + (tid & ~63)) * 16];                     \
      gload_lds16(g, l);                                                        \
    }                                                                           \
  }

#define CVT8(dsth, dstm, va, vb)                                                \
  {                                                                             \
    const float xv_[8] = {(va).x, (va).y, (va).z, (va).w,                       \
                          (vb).x, (vb).y, (vb).z, (vb).w};                      \
    _Pragma("unroll") for (int j = 0; j < 8; ++j) {                             \
      const float v = xv_[j] * 16.f;                                            \
      const _Float16 h = (_Float16)v;                                           \
      const float r = (v - (float)h) * 2048.f;                                  \
      (dsth)[j] = h;                                                            \
      (dstm)[j] = (_Float16)r;                                                  \
    }                                                                           \
  }

#define BODY(kc_, WAITS, DO_STAGE, DO_XL)                                       \
  {                                                                             \
    const int kc__ = (kc_);                                                     \
    if (DO_XL) {                                                                \
      const int nb = (kc__ + 1 < NKC) ? kc__ + 1 : 0;                           \
      xn0 = *(const float4*)(xsrcA + (size_t)nb * BK);                          \
      xn1 = *(const float4*)(xsrcA + (size_t)nb * BK + 4);                      \
      xn2 = *(const float4*)(xsrcB + (size_t)nb * BK);                          \
      xn3 = *(const float4*)(xsrcB + (size_t)nb * BK + 4);                      \
    }                                                                           \
    asm volatile("s_waitcnt vmcnt(" WAITS ")" ::: "memory");                    \
    __builtin_amdgcn_s_barrier();                                               \
    __builtin_amdgcn_sched_barrier(0);                                          \
    if (DO_STAGE) STAGE_W((kc__ + 3) & 3, kc__ + 3);                            \
    const int wof = (kc__ & 3) * 32768;                                         \
    f16x8 bfr[2][4];                                                            \
    _Pragma("unroll") for (int p = 0; p < 2; ++p)                               \
        _Pragma("unroll") for (int fn = 0; fn < 4; ++fn)                        \
            bfr[p][fn] = *(const f16x8*)&smem[wof + p * 16384 +                 \
                                              (c4 * 256 +                      \
                                               (wn * 64 + fn * 16 + r16)) *    \
                                                  16];                          \
    f16x8 af[2][2];                                                             \
    CVT8(af[0][0], af[1][0], xc0, xc1);                                         \
    CVT8(af[0][1], af[1][1], xc2, xc3);                                         \
    __builtin_amdgcn_s_setprio(1);                                              \
    _Pragma("unroll") for (int fm = 0; fm < 2; ++fm)                            \
        _Pragma("unroll") for (int fn = 0; fn < 4; ++fn) {                      \
      acc0[fm][fn] = __builtin_amdgcn_mfma_f32_16x16x32_f16(                    \
          af[0][fm], bfr[0][fn], acc0[fm][fn], 0, 0, 0);                        \
      f32x4 s = acc1[fm][fn];                                                   \
      s = __builtin_amdgcn_mfma_f32_16x16x32_f16(af[0][fm], bfr[1][fn], s, 0, 0, 0); \
      s = __builtin_amdgcn_mfma_f32_16x16x32_f16(af[1][fm], bfr[0][fn], s, 0, 0, 0); \
      acc1[fm][fn] = s;                                                         \
      acc2[fm][fn] = __builtin_amdgcn_mfma_f32_16x16x32_f16(                    \
          af[1][fm], bfr[1][fn], acc2[fm][fn], 0, 0, 0);                        \
    }                                                                           \
    __builtin_amdgcn_s_setprio(0);                                              \
    if (DO_XL) { xc0 = xn0; xc1 = xn1; xc2 = xn2; xc3 = xn3; }                  \
  }

  // prologue: X chunk 0 into regs; W chunks 0..2 into ring bufs 0..2
  xc0 = *(const float4*)(xsrcA);
  xc1 = *(const float4*)(xsrcA + 4);
  xc2 = *(const float4*)(xsrcB);
  xc3 = *(const float4*)(xsrcB + 4);
  STAGE_W(0, 0);
  STAGE_W(1, 1);
  STAGE_W(2, 2);

  // steady state: per iter issues X(kc+1) x4 then (post-barrier) W(kc+3) x4;
  // exactly 8 vmem ops are issued after X(kc) -> vmcnt(8) guarantees X(kc)
  // and W(kc) complete. Tail: no more stages -> 4 then 0.
  for (int kc = 0; kc < NKC - 3; ++kc) BODY(kc, "8", 1, 1);  // 0..124
  BODY(NKC - 3, "8", 0, 1);                                  // 125
  BODY(NKC - 2, "4", 0, 1);                                  // 126
  BODY(NKC - 1, "0", 0, 0);                                  // 127

  // ---- epilogue: logits -> LDS [64][260] fp32, then fused top-k ----
  __syncthreads();
  float* lg = (float*)smem;
#pragma unroll
  for (int fm = 0; fm < 2; ++fm)
#pragma unroll
    for (int fn = 0; fn < 4; ++fn)
#pragma unroll
      for (int r = 0; r < 4; ++r) {
        const int t = wm * 32 + fm * 16 + c4 * 4 + r;
        const int n = wn * 64 + fn * 16 + r16;
        lg[t * 260 + n] =
            fmaf(acc2[fm][fn][r], C2,
                 fmaf(acc1[fm][fn][r], C1, acc0[fm][fn][r] * C0));
      }
  __syncthreads();

  // phase 2 (verified round-1/2/3 logic): wave processes 8 tokens sequentially
  const float4 bv = *(const float4*)(bias + lane * 4);
  for (int i = 0; i < 8; ++i) {
    const int t = wave * 8 + i;
    const float4 lgv = *(const float4*)&lg[t * 260 + lane * 4];

    const float s0 = 1.f / (1.f + expf(-lgv.x));
    const float s1 = 1.f / (1.f + expf(-lgv.y));
    const float s2 = 1.f / (1.f + expf(-lgv.z));
    const float s3 = 1.f / (1.f + expf(-lgv.w));

    const float c0 = s0 + bv.x, c1 = s1 + bv.y, c2 = s2 + bv.z, c3 = s3 + bv.w;

    // lane-local top2 of 4
    float m1 = fmaxf(c0, c1), m2 = fminf(c0, c1);
    if (c2 > m1) { m2 = m1; m1 = c2; } else m2 = fmaxf(m2, c2);
    if (c3 > m1) { m2 = m1; m1 = c3; } else m2 = fmaxf(m2, c3);
#pragma unroll
    for (int off = 1; off < 8; off <<= 1) {
      const float o1 = __shfl_xor(m1, off);
      const float o2 = __shfl_xor(m2, off);
      if (o1 > m1) { m2 = fmaxf(m1, o2); m1 = o1; }
      else m2 = fmaxf(m2, o1);
    }
    const float gs = m1 + m2;  // group score (identical across the 8 lanes)

    const int gme = lane >> 3;
    int rank = 0;
#pragma unroll
    for (int j = 0; j < 8; ++j) {
      const float gj = __shfl(gs, j * 8);
      rank += ((gj > gs) || (gj == gs && j < gme)) ? 1 : 0;
    }
    const bool sel = rank < 4;

    const float NEG = -INFINITY;
    float q0 = sel ? c0 : NEG, q1 = sel ? c1 : NEG;
    float q2 = sel ? c2 : NEG, q3 = sel ? c3 : NEG;

    float sum = 0.f;
    int my_e = 0;
    float my_w = 0.f;
#pragma unroll
    for (int r = 0; r < 8; ++r) {
      float v = q0; int ix = 0;
      if (q1 > v) { v = q1; ix = 1; }
      if (q2 > v) { v = q2; ix = 2; }
      if (q3 > v) { v = q3; ix = 3; }
      int e = lane * 4 + ix;
#pragma unroll
      for (int off = 1; off < 64; off <<= 1) {
        const float v2 = __shfl_xor(v, off);
        const int e2 = __shfl_xor(e, off);
        const bool take = (v2 > v) || (v2 == v && e2 < e);
        v = take ? v2 : v;
        e = take ? e2 : e;
      }
      const int slot = e & 3, owner = e >> 2;
      const float svs = (slot == 0) ? s0 : ((slot == 1) ? s1 : ((slot == 2) ? s2 : s3));
      const float wgt = __shfl(svs, owner);
      sum += wgt;
      if (lane == r) { my_e = e; my_w = wgt; }
      const bool own = (lane == owner);
      q0 = (own && slot == 0) ? NEG : q0;
      q1 = (own && slot == 1) ? NEG : q1;
      q2 = (own && slot == 2) ? NEG : q2;
      q3 = (own && slot == 3) ? NEG : q3;
    }

    if (lane < 8) {
      const float denom = sum + 1e-20f;
      const long tg = bm0 + t;
      out[tg * 8 + lane] = (float)my_e;
      out[(long)T * 8 + tg * 8 + lane] = my_w / denom * 2.5f;
    }
  }
}

// ---------------------------------------------------------------------------
extern "C" void kernel_launch(void* const* d_in, const int* in_sizes, int n_in,
                              void* d_out, int out_size, void* d_ws, size_t ws_size,
                              hipStream_t stream) {
  const float* X = (const float*)d_in[0];   // [T, 4096]
  const float* W = (const float*)d_in[1];   // [256, 4096]
  const float* B = (const float*)d_in[2];   // [256]
  float* out = (float*)d_out;
  const int T = in_sizes[0] / Hdim;         // 16384

  _Float16* planes = (_Float16*)d_ws;       // 2 x 2 MB = 4 MB scratch

  convert_w<<<512, 256, 0, stream>>>(W, planes);
  moe_gate_fused<<<T / BM, 512, 0, stream>>>(X, planes, B, out, T);
}

// Round 5
// 223.232 us; speedup vs baseline: 1.2782x; 1.2782x over previous
//
#include <hip/hip_runtime.h>
#include <math.h>

#define Hdim 4096
#define NE 256
#define BM 32
#define BK 32
#define NKC (Hdim / BK)          // 128 K-chunks
#define PLANE_ELEMS (Hdim * NE)  // f16 elements per plane (1,048,576 = 2 MB)
#define PLANE_BYTES (PLANE_ELEMS * 2)

// Scales (exact powers of two; undone in epilogue):
//   W' = 64*w, X' = 16*x, m-planes additionally *2048.
//   logit = (acc0 + acc1*2^-11 + acc2*2^-22) * 2^-10
#define C0 9.765625e-4f            // 2^-10
#define C1 4.76837158203125e-7f    // 2^-21
#define C2 2.3283064365386963e-10f // 2^-32

typedef _Float16 f16x8 __attribute__((ext_vector_type(8)));
typedef _Float16 f16x4 __attribute__((ext_vector_type(4)));
typedef float f32x4 __attribute__((ext_vector_type(4)));

__device__ __forceinline__ void gload_lds16(const void* g, void* l) {
  __builtin_amdgcn_global_load_lds((const __attribute__((address_space(1))) void*)g,
                                   (__attribute__((address_space(3))) void*)l, 16, 0, 0);
}

// ---------------------------------------------------------------------------
// W [256][4096] fp32 -> 2 f16 planes: h = f16(64w), m = f16((64w - h)*2048).
// Plane layout: [k8 0..511][n 0..255] chunks of 8 f16 (16 B): element (n,k)
// at plane + ((k/8)*256 + n)*8 + k%8 — the exact LDS image staged per chunk.
// ---------------------------------------------------------------------------
__global__ __launch_bounds__(256)
void convert_w(const float* __restrict__ W, _Float16* __restrict__ pl) {
  const int id = blockIdx.x * 256 + threadIdx.x;  // 0 .. 131071
  const int k8 = id & 511;
  const int n = id >> 9;
  const float* src = W + (long)n * Hdim + k8 * 8;
  const float4 x0 = *(const float4*)src;
  const float4 x1 = *(const float4*)(src + 4);
  const float xv[8] = {x0.x, x0.y, x0.z, x0.w, x1.x, x1.y, x1.z, x1.w};
  f16x8 vh, vm;
#pragma unroll
  for (int j = 0; j < 8; ++j) {
    const float v = xv[j] * 64.f;
    const _Float16 h = (_Float16)v;
    const float r = (v - (float)h) * 2048.f;
    vh[j] = h;
    vm[j] = (_Float16)r;
  }
  const long co = ((long)k8 * NE + n) * 8;
  *(f16x8*)(pl + co) = vh;
  *(f16x8*)(pl + PLANE_ELEMS + co) = vm;
}

// ---------------------------------------------------------------------------
// Fused: logits = X @ W^T via 4-product split-f16 MFMA, then top-k epilogue.
// Round-3 verified structure (double-buffer + __syncthreads, compiler-
// scheduled) with BM=32 / 256 threads (4 waves, one fn-quadrant each) so
// grid = 512 = 2 blocks/CU: cross-block TLP hides the per-chunk barrier
// drain (m114 mechanism). LDS 72 KB: W bufs 2x32KB @0, X bufs 2x4KB @65536.
// ---------------------------------------------------------------------------
__global__ __launch_bounds__(256, 2)
void moe_gate_fused(const float* __restrict__ X, const _Float16* __restrict__ pl,
                    const float* __restrict__ bias, float* __restrict__ out, int T) {
  __shared__ __align__(16) unsigned char smem[73728];
  const int tid = threadIdx.x;
  const int lane = tid & 63, wave = tid >> 6;      // wave = fn-quadrant (0..3)
  const int r16 = lane & 15, c4 = lane >> 4;
  const long bm0 = (long)blockIdx.x * BM;

  f32x4 acc0[2][4], acc1[2][4], acc2[2][4];
#pragma unroll
  for (int i = 0; i < 2; ++i)
#pragma unroll
    for (int j = 0; j < 4; ++j) {
      acc0[i][j] = (f32x4)(0.f);
      acc1[i][j] = (f32x4)(0.f);
      acc2[i][j] = (f32x4)(0.f);
    }

  // X staging geometry: thread -> (token xm 0..31, float4-slot xf 0..7)
  const int xm = tid >> 3;
  const int xf = tid & 7;
  const float* xsrc = X + (bm0 + xm) * (long)Hdim + xf * 4;
  const int xws = ((xf >> 1) * 32 + xm) * 16 + (xf & 1) * 8;  // within one plane

#define STAGE_W(b, kc)                                                          \
  {                                                                             \
    _Pragma("unroll") for (int p = 0; p < 2; ++p)                               \
        _Pragma("unroll") for (int i = 0; i < 4; ++i) {                         \
      const char* g = (const char*)pl + (size_t)p * PLANE_BYTES +               \
                      (size_t)(kc) * 16384 + (size_t)(i * 256 + tid) * 16;      \
      void* l = (void*)&smem[(b) * 32768 + p * 16384 +                          \
                             (i * 256 + (tid & ~63)) * 16];                     \
      gload_lds16(g, l);                                                        \
    }                                                                           \
  }

#define WRITE_X(b, xr)                                                          \
  {                                                                             \
    f16x4 vh, vm;                                                               \
    const float xa[4] = {(xr).x, (xr).y, (xr).z, (xr).w};                       \
    _Pragma("unroll") for (int j = 0; j < 4; ++j) {                             \
      const float v = xa[j] * 16.f;                                             \
      const _Float16 h = (_Float16)v;                                           \
      const float r = (v - (float)h) * 2048.f;                                  \
      vh[j] = h;                                                                \
      vm[j] = (_Float16)r;                                                      \
    }                                                                           \
    const int xo = 65536 + (b) * 4096;                                          \
    *(f16x4*)&smem[xo + 0 * 2048 + xws] = vh;                                   \
    *(f16x4*)&smem[xo + 1 * 2048 + xws] = vm;                                   \
  }

#define COMPUTE(b)                                                              \
  {                                                                             \
    const int wof = (b) * 32768;                                                \
    const int xo = 65536 + (b) * 4096;                                          \
    f16x8 af[2][2], bfr[2][4];                                                  \
    _Pragma("unroll") for (int p = 0; p < 2; ++p) {                             \
      _Pragma("unroll") for (int fm = 0; fm < 2; ++fm)                          \
          af[p][fm] = *(const f16x8*)&smem[xo + p * 2048 +                      \
                                           (c4 * 32 + fm * 16 + r16) * 16];     \
      _Pragma("unroll") for (int fn = 0; fn < 4; ++fn)                          \
          bfr[p][fn] = *(const f16x8*)&smem[wof + p * 16384 +                   \
                                            (c4 * 256 +                        \
                                             (wave * 64 + fn * 16 + r16)) * 16];\
    }                                                                           \
    _Pragma("unroll") for (int fm = 0; fm < 2; ++fm)                            \
        _Pragma("unroll") for (int fn = 0; fn < 4; ++fn) {                      \
      acc0[fm][fn] = __builtin_amdgcn_mfma_f32_16x16x32_f16(                    \
          af[0][fm], bfr[0][fn], acc0[fm][fn], 0, 0, 0);                        \
      f32x4 s = acc1[fm][fn];                                                   \
      s = __builtin_amdgcn_mfma_f32_16x16x32_f16(af[0][fm], bfr[1][fn], s, 0, 0, 0); \
      s = __builtin_amdgcn_mfma_f32_16x16x32_f16(af[1][fm], bfr[0][fn], s, 0, 0, 0); \
      acc1[fm][fn] = s;                                                         \
      acc2[fm][fn] = __builtin_amdgcn_mfma_f32_16x16x32_f16(                    \
          af[1][fm], bfr[1][fn], acc2[fm][fn], 0, 0, 0);                        \
    }                                                                           \
  }

  // prologue
  STAGE_W(0, 0);
  {
    const float4 x0 = *(const float4*)(xsrc);
    WRITE_X(0, x0);
  }
  __syncthreads();

  for (int kc = 0; kc < NKC; ++kc) {
    const int cb = kc & 1;
    float4 xn;
    const bool more = (kc + 1 < NKC);
    if (more) {
      STAGE_W(cb ^ 1, kc + 1);
      xn = *(const float4*)(xsrc + (size_t)(kc + 1) * BK);  // issue early (T14)
    }
    COMPUTE(cb);
    if (more) WRITE_X(cb ^ 1, xn);  // write late, after compute
    __syncthreads();
  }

  // ---- epilogue: logits -> LDS [32][260] fp32, then fused top-k ----
  float* lg = (float*)smem;
#pragma unroll
  for (int fm = 0; fm < 2; ++fm)
#pragma unroll
    for (int fn = 0; fn < 4; ++fn)
#pragma unroll
      for (int r = 0; r < 4; ++r) {
        const int t = fm * 16 + c4 * 4 + r;
        const int n = wave * 64 + fn * 16 + r16;
        lg[t * 260 + n] =
            fmaf(acc2[fm][fn][r], C2,
                 fmaf(acc1[fm][fn][r], C1, acc0[fm][fn][r] * C0));
      }
  __syncthreads();

  // phase 2 (verified rounds 1-4 logic): wave processes 8 tokens sequentially
  const float4 bv = *(const float4*)(bias + lane * 4);
  for (int i = 0; i < 8; ++i) {
    const int t = wave * 8 + i;
    const float4 lgv = *(const float4*)&lg[t * 260 + lane * 4];

    const float s0 = 1.f / (1.f + expf(-lgv.x));
    const float s1 = 1.f / (1.f + expf(-lgv.y));
    const float s2 = 1.f / (1.f + expf(-lgv.z));
    const float s3 = 1.f / (1.f + expf(-lgv.w));

    const float c0 = s0 + bv.x, c1 = s1 + bv.y, c2 = s2 + bv.z, c3 = s3 + bv.w;

    // lane-local top2 of 4
    float m1 = fmaxf(c0, c1), m2 = fminf(c0, c1);
    if (c2 > m1) { m2 = m1; m1 = c2; } else m2 = fmaxf(m2, c2);
    if (c3 > m1) { m2 = m1; m1 = c3; } else m2 = fmaxf(m2, c3);
#pragma unroll
    for (int off = 1; off < 8; off <<= 1) {
      const float o1 = __shfl_xor(m1, off);
      const float o2 = __shfl_xor(m2, off);
      if (o1 > m1) { m2 = fmaxf(m1, o2); m1 = o1; }
      else m2 = fmaxf(m2, o1);
    }
    const float gs = m1 + m2;  // group score (identical across the 8 lanes)

    const int gme = lane >> 3;
    int rank = 0;
#pragma unroll
    for (int j = 0; j < 8; ++j) {
      const float gj = __shfl(gs, j * 8);
      rank += ((gj > gs) || (gj == gs && j < gme)) ? 1 : 0;
    }
    const bool sel = rank < 4;

    const float NEG = -INFINITY;
    float q0 = sel ? c0 : NEG, q1 = sel ? c1 : NEG;
    float q2 = sel ? c2 : NEG, q3 = sel ? c3 : NEG;

    float sum = 0.f;
    int my_e = 0;
    float my_w = 0.f;
#pragma unroll
    for (int r = 0; r < 8; ++r) {
      float v = q0; int ix = 0;
      if (q1 > v) { v = q1; ix = 1; }
      if (q2 > v) { v = q2; ix = 2; }
      if (q3 > v) { v = q3; ix = 3; }
      int e = lane * 4 + ix;
#pragma unroll
      for (int off = 1; off < 64; off <<= 1) {
        const float v2 = __shfl_xor(v, off);
        const int e2 = __shfl_xor(e, off);
        const bool take = (v2 > v) || (v2 == v && e2 < e);
        v = take ? v2 : v;
        e = take ? e2 : e;
      }
      const int slot = e & 3, owner = e >> 2;
      const float svs = (slot == 0) ? s0 : ((slot == 1) ? s1 : ((slot == 2) ? s2 : s3));
      const float wgt = __shfl(svs, owner);
      sum += wgt;
      if (lane == r) { my_e = e; my_w = wgt; }
      const bool own = (lane == owner);
      q0 = (own && slot == 0) ? NEG : q0;
      q1 = (own && slot == 1) ? NEG : q1;
      q2 = (own && slot == 2) ? NEG : q2;
      q3 = (own && slot == 3) ? NEG : q3;
    }

    if (lane < 8) {
      const float denom = sum + 1e-20f;
      const long tg = bm0 + t;
      out[tg * 8 + lane] = (float)my_e;
      out[(long)T * 8 + tg * 8 + lane] = my_w / denom * 2.5f;
    }
  }
}

// ---------------------------------------------------------------------------
extern "C" void kernel_launch(void* const* d_in, const int* in_sizes, int n_in,
                              void* d_out, int out_size, void* d_ws, size_t ws_size,
                              hipStream_t stream) {
  const float* X = (const float*)d_in[0];   // [T, 4096]
  const float* W = (const float*)d_in[1];   // [256, 4096]
  const float* B = (const float*)d_in[2];   // [256]
  float* out = (float*)d_out;
  const int T = in_sizes[0] / Hdim;         // 16384

  _Float16* planes = (_Float16*)d_ws;       // 2 x 2 MB = 4 MB scratch

  convert_w<<<512, 256, 0, stream>>>(W, planes);
  moe_gate_fused<<<T / BM, 256, 0, stream>>>(X, planes, B, out, T);
}